// Round 15
// baseline (209.522 us; speedup 1.0000x reference)
//
#include <hip/hip_runtime.h>
#include <stdint.h>
#include <math.h>

#define NLVL 5
#define NIMG 4
#define NGRP (NIMG * NLVL)
#define M_TOT 4768
#define POST_K 1000
#define NEGV  (-1e9f)
#define CAP 2048
#define BPI 128         // data-pass units per image (2048-elem units)
#define TRI_W 7680      // sum over q of 64q words, column-block-major
#define RD_SPLIT 8      // rank-decode sub-blocks per group
#define UCAP 2048       // per-unit candidate region capacity

__constant__ int c_hwa[NLVL]  = {196608, 49152, 12288, 3072, 768};
__constant__ int c_k[NLVL]    = {1000, 1000, 1000, 1000, 768};
__constant__ int c_base[NLVL] = {0, 1000, 2000, 3000, 4000};
__constant__ int c_cnt[NLVL]  = {2048, 2048, 2048, 3072, 768};
__constant__ int c_us[NLVL]   = {0, 96, 120, 126, 127};  // unit start per level (within image)
__constant__ int c_un[NLVL]   = {96, 24, 6, 1, 1};       // unit count per level
// Speculative per-level key thresholds (flipf of score): expected candidate
// count ~1550 per group for N(0,1) logits; validated + repaired inline in
// kRankDecode's fallback path.
__constant__ uint32_t c_T0[NLVL] = {0xC019999Au, 0xBFECCCCDu, 0xBF933333u, 0x80000000u, 0x00000000u};

struct Ptrs {
    const float* logits[NLVL];
    const float* deltas[NLVL];
    const float* anchors[NLVL];
};

__device__ __forceinline__ uint32_t flipf(float f) {
    uint32_t b = __float_as_uint(f);
    return (b & 0x80000000u) ? ~b : (b | 0x80000000u);
}
__device__ __forceinline__ float unflipf(uint32_t key) {
    uint32_t b = (key & 0x80000000u) ? (key & 0x7FFFFFFFu) : ~key;
    return __uint_as_float(b);
}
__device__ __forceinline__ float rdlane_f(float v, int l) {
    return __uint_as_float((uint32_t)__builtin_amdgcn_readlane((int)__float_as_uint(v), l));
}

__device__ __forceinline__ void grp_decompose(int g, int& img, int& lvl, int& off, int& cnt) {
    img = g / BPI;
    int r = g % BPI;
    if (r < 96)       { lvl = 0; off = r * 2048; }
    else if (r < 120) { lvl = 1; off = (r - 96) * 2048; }
    else if (r < 126) { lvl = 2; off = (r - 120) * 2048; }
    else if (r < 127) { lvl = 3; off = 0; }
    else              { lvl = 4; off = 0; }
    cnt = c_cnt[lvl];
}

// wave64 OR-reduce via DPP, result uniform.
__device__ __forceinline__ uint32_t wave_or32(uint32_t v) {
    v |= (uint32_t)__builtin_amdgcn_update_dpp(0, (int)v, 0x111, 0xf, 0xf, true); // row_shr:1
    v |= (uint32_t)__builtin_amdgcn_update_dpp(0, (int)v, 0x112, 0xf, 0xf, true); // row_shr:2
    v |= (uint32_t)__builtin_amdgcn_update_dpp(0, (int)v, 0x114, 0xf, 0xf, true); // row_shr:4
    v |= (uint32_t)__builtin_amdgcn_update_dpp(0, (int)v, 0x118, 0xf, 0xf, true); // row_shr:8
    v |= (uint32_t)__builtin_amdgcn_update_dpp(0, (int)v, 0x142, 0xf, 0xf, true); // row_bcast:15
    v |= (uint32_t)__builtin_amdgcn_update_dpp(0, (int)v, 0x143, 0xf, 0xf, true); // row_bcast:31
    return (uint32_t)__builtin_amdgcn_readlane((int)v, 63);
}

// ---------------------------------------------------------------------------
// Speculative single-pass compaction into PRIVATE per-unit regions (2048-elem
// units, 512 blocks = 2/CU). No global atomics, no pre-zeroed counters.
// ---------------------------------------------------------------------------
__global__ void kCompactSpec(Ptrs p, uint32_t* __restrict__ ucnt,
                             uint64_t* __restrict__ pk2) {
    int img, lvl, off, cnt;
    const int u = blockIdx.x;
    grp_decompose(u, img, lvl, off, cnt);
    const int tid = threadIdx.x;
    const float* lg = p.logits[lvl] + (size_t)img * c_hwa[lvl] + off;
    const uint32_t T = c_T0[lvl];

    __shared__ uint32_t scnt;
    __shared__ uint64_t sbuf[3072];
    if (tid == 0) scnt = 0u;
    __syncthreads();

    const int nvec = cnt >> 2;
    const float4* lg4 = (const float4*)lg;
    for (int v = tid; v < nvec; v += 256) {
        float4 x = lg4[v];
        float xs[4] = {x.x, x.y, x.z, x.w};
        #pragma unroll
        for (int c = 0; c < 4; ++c) {
            uint32_t key = flipf(xs[c]);
            if (key >= T) {
                uint32_t pos = atomicAdd(&scnt, 1u);
                uint32_t eidx = (uint32_t)(off + 4 * v + c);
                sbuf[pos] = ((uint64_t)key << 32) | (uint32_t)(~eidx);
            }
        }
    }
    __syncthreads();
    const uint32_t n = scnt;
    if (tid == 0) ucnt[u] = n;                 // plain store, private slot
    const uint32_t nw = min(n, (uint32_t)UCAP);
    uint64_t* pk = pk2 + (size_t)u * UCAP;
    for (uint32_t i = tid; i < nw; i += 256) pk[i] = sbuf[i];
}

// ---------------------------------------------------------------------------
// Rank + decode, with inline exact fallback. RD_SPLIT blocks per group.
// Unit counts loaded in PARALLEL into LDS, prefix by tid0 over LDS (fast).
// ---------------------------------------------------------------------------
__global__ void kRankDecode(Ptrs p, const uint32_t* __restrict__ ucnt,
                            const uint64_t* __restrict__ pk2,
                            float* __restrict__ cand_box,
                            float* __restrict__ cand_score) {
    #pragma clang fp contract(off)
    const int blk = blockIdx.x;          // grp * RD_SPLIT + sub
    const int grp = blk / RD_SPLIT;
    const int sub = blk % RD_SPLIT;
    const int img = grp / NLVL;
    const int lvl = grp % NLVL;
    const int n    = c_hwa[lvl];
    const int k    = c_k[lvl];
    const int base = c_base[lvl];
    const int tid = threadIdx.x;
    const int nu  = c_un[lvl];
    const int u0  = img * BPI + c_us[lvl];
    const int c0  = sub * (CAP / RD_SPLIT);

    __shared__ uint64_t K[CAP];
    __shared__ uint32_t sucnt[96];
    __shared__ int soff[97];
    __shared__ uint32_t hist[256];
    __shared__ uint32_t sh_pre, sh_rem, scnt2;
    __shared__ int scc, sbad;

    if (tid < nu) sucnt[tid] = ucnt[u0 + tid];   // parallel loads
    __syncthreads();
    if (tid == 0) {
        int o = 0, bad = 0;
        for (int i = 0; i < nu; ++i) {
            int c = (int)sucnt[i];
            soff[i] = o;
            if (c > UCAP) bad = 1;
            o += c;
        }
        soff[nu] = o;
        scc = o; sbad = bad;
    }
    __syncthreads();
    int cc = scc;
    const bool fb = sbad || (cc < k) || (cc > CAP);

    if (!fb) {
        if (c0 >= cc) return;            // block-uniform
        // latency-batched gather: 8 independent loads/thread, one wait
        uint64_t vb[8];
        int tt[8];
        #pragma unroll
        for (int q = 0; q < 8; ++q) {
            const int t = tid + q * 256;
            tt[q] = t;
            if (t < cc) {
                int lo2 = 0, hi2 = nu - 1;
                while (lo2 < hi2) {
                    int mid = (lo2 + hi2 + 1) >> 1;
                    if (soff[mid] <= t) lo2 = mid; else hi2 = mid - 1;
                }
                vb[q] = pk2[(size_t)(u0 + lo2) * UCAP + (t - soff[lo2])];
            }
        }
        #pragma unroll
        for (int q = 0; q < 8; ++q)
            if (tt[q] < cc) K[tt[q]] = vb[q];
        __syncthreads();
    } else {
        // exact fallback: radix select + recompaction (block-local)
        const float* lg = p.logits[lvl] + (size_t)img * n;
        if (tid == 0) { sh_pre = 0u; sh_rem = (uint32_t)k; scnt2 = 0u; }
        for (int pass = 0; pass < 4; ++pass) {
            hist[tid] = 0u;
            __syncthreads();
            const int shift = 24 - 8 * pass;
            const uint32_t pre = sh_pre;
            for (int i = tid; i < n; i += 256) {
                uint32_t key = flipf(lg[i]);
                if (pass == 0 || (key >> (shift + 8)) == pre)
                    atomicAdd(&hist[(key >> shift) & 255u], 1u);
            }
            __syncthreads();
            if (tid == 0) {
                uint32_t rem = sh_rem;
                int d = 255;
                for (; d > 0; --d) {
                    uint32_t c = hist[d];
                    if (rem <= c) break;
                    rem -= c;
                }
                sh_rem = rem;
                sh_pre = (pre << 8) | (uint32_t)d;
            }
            __syncthreads();
        }
        const uint32_t T = sh_pre;
        for (int i = tid; i < n; i += 256) {
            uint32_t key = flipf(lg[i]);
            if (key >= T) {
                uint32_t pos = atomicAdd(&scnt2, 1u);
                if (pos < CAP) K[pos] = ((uint64_t)key << 32) | (uint32_t)(~(uint32_t)i);
            }
        }
        __syncthreads();
        cc = (int)min(scnt2, (uint32_t)CAP);
        if (c0 >= cc) return;
    }

    const int c = c0 + tid;
    const uint64_t myK = (c < cc) ? K[c] : ~0ull;
    int r = 0;
    int j = 0;
    for (; j + 8 <= cc; j += 8) {
        #pragma unroll
        for (int u = 0; u < 8; ++u) r += (int)(K[j + u] > myK);
    }
    for (; j < cc; ++j) r += (int)(K[j] > myK);

    if (c >= cc || r >= k) return;

    uint32_t key = (uint32_t)(myK >> 32);
    uint32_t ic  = ~(uint32_t)(myK & 0xFFFFFFFFu);
    const float* an = p.anchors[lvl] + (size_t)ic * 4;
    const float* dl = p.deltas[lvl] + ((size_t)img * n + ic) * 4;
    float a0 = an[0], a1 = an[1], a2 = an[2], a3 = an[3];
    float wa = a2 - a0, ha = a3 - a1;
    float cxa = a0 + 0.5f * wa, cya = a1 + 0.5f * ha;
    float dx = dl[0], dy = dl[1], dw = dl[2], dh = dl[3];
    const float SC = (float)4.135166556742356;  // log(1000/16)
    dw = fminf(dw, SC);
    dh = fminf(dh, SC);
    float cx = dx * wa + cxa, cy = dy * ha + cya;
    float w = wa * expf(dw), h = ha * expf(dh);
    float x1 = cx - 0.5f * w, y1 = cy - 0.5f * h;
    float x2 = cx + 0.5f * w, y2 = cy + 0.5f * h;
    x1 = fminf(fmaxf(x1, 0.0f), 1024.0f);
    y1 = fminf(fmaxf(y1, 0.0f), 1024.0f);
    x2 = fminf(fmaxf(x2, 0.0f), 1024.0f);
    y2 = fminf(fmaxf(y2, 0.0f), 1024.0f);
    float bw = x2 - x1, bh = y2 - y1;
    float score = (bw > 0.0f && bh > 0.0f) ? unflipf(key) : NEGV;
    const int slot = base + r;
    float* ob = cand_box + ((size_t)img * M_TOT + slot) * 4;
    ob[0] = x1; ob[1] = y1; ob[2] = x2; ob[3] = y2;
    cand_score[(size_t)img * M_TOT + slot] = score;
}

// ---------------------------------------------------------------------------
// NMS phase 1: suppression bit-matrix, COLUMN-BLOCK-MAJOR; j-boxes in lanes,
// v_readlane broadcasts — pure-VALU inner loop, no LDS.
// ---------------------------------------------------------------------------
__global__ void kIou(const float* __restrict__ cand_box,
                     uint64_t* __restrict__ tri, uint64_t* __restrict__ diag) {
    #pragma clang fp contract(off)
    const int blk = blockIdx.x;      // grp*64 + w*4 + c
    const int grp = blk >> 6;
    const int w   = (blk >> 2) & 15;
    const int ch  = blk & 3;
    const int img = grp / NLVL;
    const int lvl = grp % NLVL;
    const int k    = c_k[lvl];
    const int base = c_base[lvl];
    if (64 * w >= k) return;
    const int R  = min(64 * (w + 1), k);
    const int r0 = ch * 256;
    if (r0 >= R) return;
    const int jn = min(64, k - 64 * w);
    const float lo = (float)lvl * 2048.0f;
    const int tid = threadIdx.x;
    const int lane = tid & 63;

    const int jl = (lane < jn) ? lane : 0;
    const float4 jb = *(const float4*)(cand_box + ((size_t)img * M_TOT + base + 64 * w + jl) * 4);
    const float jx1r = jb.x + lo, jy1r = jb.y + lo;
    const float jx2r = jb.z + lo, jy2r = jb.w + lo;
    const float jarr = (jx2r - jx1r) * (jy2r - jy1r);

    const int r = r0 + tid;
    const bool act = r < R;
    float rx1 = 0, ry1 = 0, rx2 = 0, ry2 = 0, ra = 0;
    if (act) {
        const float4 b = *(const float4*)(cand_box + ((size_t)img * M_TOT + base + r) * 4);
        rx1 = b.x + lo; ry1 = b.y + lo; rx2 = b.z + lo; ry2 = b.w + lo;
        ra = (rx2 - rx1) * (ry2 - ry1);
    }

    uint64_t bits = 0ull;
    #pragma unroll 4
    for (int jj = 0; jj < jn; ++jj) {
        const float bx1 = rdlane_f(jx1r, jj);
        const float by1 = rdlane_f(jy1r, jj);
        const float bx2 = rdlane_f(jx2r, jj);
        const float by2 = rdlane_f(jy2r, jj);
        const float bar = rdlane_f(jarr, jj);
        const int j = 64 * w + jj;
        if (j > r) {
            float ltx = fmaxf(rx1, bx1);
            float lty = fmaxf(ry1, by1);
            float rbx = fminf(rx2, bx2);
            float rby = fminf(ry2, by2);
            float wx = fmaxf(rbx - ltx, 0.0f);
            float wy = fmaxf(rby - lty, 0.0f);
            float inter = wx * wy;
            float denom = ((ra + bar) - inter) + 1e-9f;
            if (inter / denom > 0.7f) bits |= (1ull << jj);
        }
    }

    if (act) {
        if ((r >> 6) == w) diag[(size_t)grp * 1024 + r] = bits;
        else               tri[(size_t)grp * TRI_W + 32 * w * (w - 1) + r] = bits;
    }
}

// ---------------------------------------------------------------------------
// Fused scan + merge + output, one block (1024 thr) per image.
// Waves 0-4 each run the verified one-wave greedy scan for their level
// (kept bits to LDS), one barrier, then merge-rank + partition + output.
// ---------------------------------------------------------------------------
__device__ __forceinline__ int bs_count_ge(const uint32_t* a, int n, uint32_t x) {
    int lo = 0, hi = n;
    while (lo < hi) { int mid = (lo + hi) >> 1; if (a[mid] >= x) lo = mid + 1; else hi = mid; }
    return lo;
}
__device__ __forceinline__ int bs_count_gt(const uint32_t* a, int n, uint32_t x) {
    int lo = 0, hi = n;
    while (lo < hi) { int mid = (lo + hi) >> 1; if (a[mid] > x) lo = mid + 1; else hi = mid; }
    return lo;
}

__global__ void kScanMerge(const float* __restrict__ cand_box,
                           const float* __restrict__ cand_score,
                           const uint64_t* __restrict__ tri,
                           const uint64_t* __restrict__ diag,
                           float* __restrict__ out) {
    const int img = blockIdx.x;
    const int tid = threadIdx.x;   // 1024
    const int lane = tid & 63, wave = tid >> 6;

    // uA: sdiag[5][1024] u64 (scan) then vkey[5120]+ord[4768] u32 (merge)
    __shared__ __align__(16) char uA[40960];
    __shared__ uint32_t skept[M_TOT];
    __shared__ uint64_t sinv5[NLVL][16];
    __shared__ uint32_t wsum[NLVL][16];
    __shared__ int wtot[16];

    // ================= scan phase: wave w < 5 does group (img, w) ========
    if (wave < NLVL) {
        const int lvl = wave;
        const int grp = img * NLVL + lvl;
        const int k    = c_k[lvl];
        const int base = c_base[lvl];
        uint64_t* sdiag = ((uint64_t*)uA) + lvl * 1024;

        const uint64_t* dg_g = diag + (size_t)grp * 1024;
        #pragma unroll
        for (int s = 0; s < 16; ++s) {
            const int r = 64 * s + lane;
            uint64_t d = (r < k) ? dg_g[r] : 0ull;
            sdiag[r] = d;
            float sc = (r < k) ? cand_score[(size_t)img * M_TOT + base + r] : NEGV;
            uint64_t iv = __ballot(sc <= -5e8f);
            if (lane == 0) sinv5[lvl][s] = iv;
        }
        // single wave per region: program order suffices, no barrier here

        const uint64_t* trig = tri + (size_t)grp * TRI_W;
        uint32_t mykept = 0u;
        const int nstage = (k + 63) >> 6;

        #pragma unroll 1
        for (int q = 0; q < nstage; ++q) {
            const uint64_t* tq = trig + 32 * q * (q - 1);
            uint64_t vals[15];
            #pragma unroll
            for (int s = 0; s < 15; ++s)
                if (s < q) vals[s] = tq[64 * s + lane];
            uint64_t v = 0ull;
            #pragma unroll
            for (int s = 0; s < 15; ++s)
                if (s < q) {
                    uint64_t msk = (uint64_t)0 - (uint64_t)((mykept >> s) & 1u);
                    v |= vals[s] & msk;
                }
            const uint32_t vlo = wave_or32((uint32_t)v);
            const uint32_t vhi = wave_or32((uint32_t)(v >> 32));
            const uint64_t invq = sinv5[lvl][q];
            const uint32_t ivlo = __builtin_amdgcn_readfirstlane((uint32_t)invq);
            const uint32_t ivhi = __builtin_amdgcn_readfirstlane((uint32_t)(invq >> 32));
            uint64_t rem = ~((((uint64_t)ivhi << 32) | (uint64_t)ivlo)
                           | (((uint64_t)vhi  << 32) | (uint64_t)vlo));

            const uint64_t darrq = sdiag[64 * q + lane];
            const uint32_t dlo = (uint32_t)darrq, dhi = (uint32_t)(darrq >> 32);
            const uint64_t nz = __ballot(darrq != 0ull);

            uint64_t kw = 0ull;
            for (;;) {
                uint64_t t = rem & nz;
                if (t == 0ull) { kw |= rem; break; }
                const int m = (int)__builtin_ctzll(t);
                const uint64_t bm = 1ull << m;
                const uint64_t lowm = bm - 1ull;
                kw |= (rem & lowm) | bm;
                const uint64_t dg =
                    ((uint64_t)(uint32_t)__builtin_amdgcn_readlane((int)dhi, m) << 32)
                  |  (uint64_t)(uint32_t)__builtin_amdgcn_readlane((int)dlo, m);
                rem &= ~(lowm | bm | dg);
            }
            mykept |= ((uint32_t)((kw >> lane) & 1ull)) << q;
        }

        #pragma unroll
        for (int s = 0; s < 16; ++s) {
            const int r = 64 * s + lane;
            if (r < k) skept[base + r] = (mykept >> s) & 1u;
        }
    }
    __syncthreads();

    // ================= merge phases (verified kMergeOut body) ============
    uint32_t* vkey = (uint32_t*)uA;            // 5120 u32
    uint32_t* ord  = ((uint32_t*)uA) + 5120;   // 4768 u32 (total 39552 B <= 40960)

    // ---- Phase 1: per-level valid ballot-scan ----
    uint32_t mykey[NLVL];
    int myvalid[NLVL], mylower[NLVL];
    #pragma unroll
    for (int L = 0; L < NLVL; ++L) {
        const int kL = c_k[L];
        const bool act = tid < kL;
        float s = act ? cand_score[(size_t)img * M_TOT + c_base[L] + tid] : NEGV;
        bool valid = act && (s > -5e8f);
        uint64_t mask = __ballot(valid);
        mylower[L] = (int)__popcll(mask & ((1ull << lane) - 1ull));
        if (lane == 0) wsum[L][wave] = (uint32_t)__popcll(mask);
        mykey[L] = flipf(s);
        myvalid[L] = valid ? 1 : 0;
    }
    __syncthreads();

    int nv[NLVL], myvpre[NLVL];
    #pragma unroll
    for (int L = 0; L < NLVL; ++L) {
        int pw = 0, tot = 0;
        #pragma unroll
        for (int w = 0; w < 16; ++w) {
            if (w < wave) pw += (int)wsum[L][w];
            tot += (int)wsum[L][w];
        }
        nv[L] = tot;
        myvpre[L] = pw + mylower[L];
        if (tid < c_k[L] && myvalid[L])
            vkey[L * 1024 + myvpre[L]] = mykey[L];
    }
    int totalValid = 0;
    #pragma unroll
    for (int L = 0; L < NLVL; ++L) totalValid += nv[L];
    __syncthreads();

    // ---- Phase 2: merge-rank each element, scatter into ord ----
    int invBase = totalValid;
    #pragma unroll
    for (int L = 0; L < NLVL; ++L) {
        const int kL = c_k[L];
        if (tid < kL) {
            const int slot = c_base[L] + tid;
            if (myvalid[L]) {
                const uint32_t x = mykey[L];
                int pos = myvpre[L];
                #pragma unroll
                for (int Lp = 0; Lp < NLVL; ++Lp) {
                    if (Lp == L) continue;
                    pos += (Lp < L) ? bs_count_ge(&vkey[Lp * 1024], nv[Lp], x)
                                    : bs_count_gt(&vkey[Lp * 1024], nv[Lp], x);
                }
                ord[pos] = (uint32_t)slot | (skept[slot] << 31);
            } else {
                const int inv_idx = tid - myvpre[L];
                ord[invBase + inv_idx] = (uint32_t)slot;  // kept=0
            }
        }
        invBase += (kL - nv[L]);
    }
    __syncthreads();

    // ---- Phase 3: stable partition by kept flag, write output ----
    const int PT = 5;
    const int pos0 = tid * PT;
    int flags[PT];
    uint32_t slots[PT];
    int lsum = 0;
    #pragma unroll
    for (int q = 0; q < PT; ++q) {
        int pp = pos0 + q;
        int kf = 0; uint32_t sl = 0;
        if (pp < M_TOT) {
            uint32_t o = ord[pp];
            sl = o & 0x7FFFFFFFu;
            kf = (int)(o >> 31);
        }
        flags[q] = kf; slots[q] = sl; lsum += kf;
    }
    int incl = lsum;
    #pragma unroll
    for (int off = 1; off < 64; off <<= 1) {
        int t = __shfl_up(incl, off, 64);
        if (lane >= off) incl += t;
    }
    if (lane == 63) wtot[wave] = incl;
    __syncthreads();
    int wpre = 0, total = 0;
    #pragma unroll
    for (int w = 0; w < 16; ++w) {
        int v = wtot[w];
        if (w < wave) wpre += v;
        total += v;
    }
    const int excl = wpre + (incl - lsum);

    int run = 0;
    #pragma unroll
    for (int q = 0; q < PT; ++q) {
        int pp = pos0 + q;
        if (pp >= M_TOT) break;
        int kf = flags[q];
        int kbefore = excl + run;
        run += kf;
        int oidx = kf ? kbefore : (total + (pp - kbefore));
        if (oidx < POST_K) {
            uint32_t sl = slots[q];
            const float4 b = *(const float4*)(cand_box + ((size_t)img * M_TOT + sl) * 4);
            float* ob = out + ((size_t)img * POST_K + oidx) * 4;
            ob[0] = b.x; ob[1] = b.y; ob[2] = b.z; ob[3] = b.w;
            out[NIMG * POST_K * 4 + (size_t)img * POST_K + oidx] =
                kf ? cand_score[(size_t)img * M_TOT + sl] : NEGV;
        }
    }
}

extern "C" void kernel_launch(void* const* d_in, const int* in_sizes, int n_in,
                              void* d_out, int out_size, void* d_ws, size_t ws_size,
                              hipStream_t stream) {
    Ptrs p;
    for (int l = 0; l < NLVL; ++l) {
        p.logits[l]  = (const float*)d_in[3 * l + 0];
        p.deltas[l]  = (const float*)d_in[3 * l + 1];
        p.anchors[l] = (const float*)d_in[3 * l + 2];
    }

    // workspace layout (~12 MB)
    char* w = (char*)d_ws;
    float* cand_box   = (float*)w;        w += (size_t)NIMG * M_TOT * 4 * sizeof(float);
    float* cand_score = (float*)w;        w += (size_t)NIMG * M_TOT * sizeof(float);
    uint64_t* pk2         = (uint64_t*)w; w += (size_t)NIMG * BPI * UCAP * sizeof(uint64_t);
    uint64_t* tri         = (uint64_t*)w; w += (size_t)NGRP * TRI_W * sizeof(uint64_t);
    uint64_t* diag        = (uint64_t*)w; w += (size_t)NGRP * 1024 * sizeof(uint64_t);
    uint32_t* ucnt        = (uint32_t*)w; w += (size_t)NIMG * BPI * sizeof(uint32_t);

    kCompactSpec<<<NIMG * BPI,       256, 0, stream>>>(p, ucnt, pk2);
    kRankDecode <<<NGRP * RD_SPLIT,  256, 0, stream>>>(p, ucnt, pk2, cand_box, cand_score);
    kIou        <<<NGRP * 64,        256, 0, stream>>>(cand_box, tri, diag);
    kScanMerge  <<<NIMG,            1024, 0, stream>>>(cand_box, cand_score, tri, diag,
                                                       (float*)d_out);
}

// Round 16
// 184.847 us; speedup vs baseline: 1.1335x; 1.1335x over previous
//
#include <hip/hip_runtime.h>
#include <stdint.h>
#include <math.h>

#define NLVL 5
#define NIMG 4
#define NGRP (NIMG * NLVL)
#define M_TOT 4768
#define POST_K 1000
#define NEGV  (-1e9f)
#define CAP 2048
#define BPI 128         // data-pass units per image (2048-elem units)
#define TRI_W 7680      // sum over q of 64q words, column-block-major
#define RD_SPLIT 8      // rank-decode sub-blocks per group
#define UCAP 2048       // per-unit candidate region capacity

__constant__ int c_hwa[NLVL]  = {196608, 49152, 12288, 3072, 768};
__constant__ int c_k[NLVL]    = {1000, 1000, 1000, 1000, 768};
__constant__ int c_base[NLVL] = {0, 1000, 2000, 3000, 4000};
__constant__ int c_cnt[NLVL]  = {2048, 2048, 2048, 3072, 768};
__constant__ int c_us[NLVL]   = {0, 96, 120, 126, 127};  // unit start per level (within image)
__constant__ int c_un[NLVL]   = {96, 24, 6, 1, 1};       // unit count per level
// Speculative per-level key thresholds (flipf of score): expected candidate
// count ~1550 per group for N(0,1) logits; validated + repaired inline in
// kRankDecode's fallback path.
__constant__ uint32_t c_T0[NLVL] = {0xC019999Au, 0xBFECCCCDu, 0xBF933333u, 0x80000000u, 0x00000000u};

struct Ptrs {
    const float* logits[NLVL];
    const float* deltas[NLVL];
    const float* anchors[NLVL];
};

__device__ __forceinline__ uint32_t flipf(float f) {
    uint32_t b = __float_as_uint(f);
    return (b & 0x80000000u) ? ~b : (b | 0x80000000u);
}
__device__ __forceinline__ float unflipf(uint32_t key) {
    uint32_t b = (key & 0x80000000u) ? (key & 0x7FFFFFFFu) : ~key;
    return __uint_as_float(b);
}
__device__ __forceinline__ float rdlane_f(float v, int l) {
    return __uint_as_float((uint32_t)__builtin_amdgcn_readlane((int)__float_as_uint(v), l));
}

__device__ __forceinline__ void grp_decompose(int g, int& img, int& lvl, int& off, int& cnt) {
    img = g / BPI;
    int r = g % BPI;
    if (r < 96)       { lvl = 0; off = r * 2048; }
    else if (r < 120) { lvl = 1; off = (r - 96) * 2048; }
    else if (r < 126) { lvl = 2; off = (r - 120) * 2048; }
    else if (r < 127) { lvl = 3; off = 0; }
    else              { lvl = 4; off = 0; }
    cnt = c_cnt[lvl];
}

// wave64 OR-reduce via DPP, result uniform.
__device__ __forceinline__ uint32_t wave_or32(uint32_t v) {
    v |= (uint32_t)__builtin_amdgcn_update_dpp(0, (int)v, 0x111, 0xf, 0xf, true); // row_shr:1
    v |= (uint32_t)__builtin_amdgcn_update_dpp(0, (int)v, 0x112, 0xf, 0xf, true); // row_shr:2
    v |= (uint32_t)__builtin_amdgcn_update_dpp(0, (int)v, 0x114, 0xf, 0xf, true); // row_shr:4
    v |= (uint32_t)__builtin_amdgcn_update_dpp(0, (int)v, 0x118, 0xf, 0xf, true); // row_shr:8
    v |= (uint32_t)__builtin_amdgcn_update_dpp(0, (int)v, 0x142, 0xf, 0xf, true); // row_bcast:15
    v |= (uint32_t)__builtin_amdgcn_update_dpp(0, (int)v, 0x143, 0xf, 0xf, true); // row_bcast:31
    return (uint32_t)__builtin_amdgcn_readlane((int)v, 63);
}

// ---------------------------------------------------------------------------
// Speculative single-pass compaction into PRIVATE per-unit regions (2048-elem
// units, 512 blocks = 2/CU). No global atomics, no pre-zeroed counters.
// ---------------------------------------------------------------------------
__global__ void kCompactSpec(Ptrs p, uint32_t* __restrict__ ucnt,
                             uint64_t* __restrict__ pk2) {
    int img, lvl, off, cnt;
    const int u = blockIdx.x;
    grp_decompose(u, img, lvl, off, cnt);
    const int tid = threadIdx.x;
    const float* lg = p.logits[lvl] + (size_t)img * c_hwa[lvl] + off;
    const uint32_t T = c_T0[lvl];

    __shared__ uint32_t scnt;
    __shared__ uint64_t sbuf[3072];
    if (tid == 0) scnt = 0u;
    __syncthreads();

    const int nvec = cnt >> 2;
    const float4* lg4 = (const float4*)lg;
    for (int v = tid; v < nvec; v += 256) {
        float4 x = lg4[v];
        float xs[4] = {x.x, x.y, x.z, x.w};
        #pragma unroll
        for (int c = 0; c < 4; ++c) {
            uint32_t key = flipf(xs[c]);
            if (key >= T) {
                uint32_t pos = atomicAdd(&scnt, 1u);
                uint32_t eidx = (uint32_t)(off + 4 * v + c);
                sbuf[pos] = ((uint64_t)key << 32) | (uint32_t)(~eidx);
            }
        }
    }
    __syncthreads();
    const uint32_t n = scnt;
    if (tid == 0) ucnt[u] = n;                 // plain store, private slot
    const uint32_t nw = min(n, (uint32_t)UCAP);
    uint64_t* pk = pk2 + (size_t)u * UCAP;
    for (uint32_t i = tid; i < nw; i += 256) pk[i] = sbuf[i];
}

// ---------------------------------------------------------------------------
// Rank + decode, with inline exact fallback. RD_SPLIT blocks per group.
// Unit counts loaded in PARALLEL into LDS, prefix by tid0 over LDS.
// ---------------------------------------------------------------------------
__global__ void kRankDecode(Ptrs p, const uint32_t* __restrict__ ucnt,
                            const uint64_t* __restrict__ pk2,
                            float* __restrict__ cand_box,
                            float* __restrict__ cand_score) {
    #pragma clang fp contract(off)
    const int blk = blockIdx.x;          // grp * RD_SPLIT + sub
    const int grp = blk / RD_SPLIT;
    const int sub = blk % RD_SPLIT;
    const int img = grp / NLVL;
    const int lvl = grp % NLVL;
    const int n    = c_hwa[lvl];
    const int k    = c_k[lvl];
    const int base = c_base[lvl];
    const int tid = threadIdx.x;
    const int nu  = c_un[lvl];
    const int u0  = img * BPI + c_us[lvl];
    const int c0  = sub * (CAP / RD_SPLIT);

    __shared__ uint64_t K[CAP];
    __shared__ uint32_t sucnt[96];
    __shared__ int soff[97];
    __shared__ uint32_t hist[256];
    __shared__ uint32_t sh_pre, sh_rem, scnt2;
    __shared__ int scc, sbad;

    if (tid < nu) sucnt[tid] = ucnt[u0 + tid];   // parallel loads
    __syncthreads();
    if (tid == 0) {
        int o = 0, bad = 0;
        for (int i = 0; i < nu; ++i) {
            int c = (int)sucnt[i];
            soff[i] = o;
            if (c > UCAP) bad = 1;
            o += c;
        }
        soff[nu] = o;
        scc = o; sbad = bad;
    }
    __syncthreads();
    int cc = scc;
    const bool fb = sbad || (cc < k) || (cc > CAP);

    if (!fb) {
        if (c0 >= cc) return;            // block-uniform
        // latency-batched gather: 8 independent loads/thread, one wait
        uint64_t vb[8];
        int tt[8];
        #pragma unroll
        for (int q = 0; q < 8; ++q) {
            const int t = tid + q * 256;
            tt[q] = t;
            if (t < cc) {
                int lo2 = 0, hi2 = nu - 1;
                while (lo2 < hi2) {
                    int mid = (lo2 + hi2 + 1) >> 1;
                    if (soff[mid] <= t) lo2 = mid; else hi2 = mid - 1;
                }
                vb[q] = pk2[(size_t)(u0 + lo2) * UCAP + (t - soff[lo2])];
            }
        }
        #pragma unroll
        for (int q = 0; q < 8; ++q)
            if (tt[q] < cc) K[tt[q]] = vb[q];
        __syncthreads();
    } else {
        // exact fallback: radix select + recompaction (block-local)
        const float* lg = p.logits[lvl] + (size_t)img * n;
        if (tid == 0) { sh_pre = 0u; sh_rem = (uint32_t)k; scnt2 = 0u; }
        for (int pass = 0; pass < 4; ++pass) {
            hist[tid] = 0u;
            __syncthreads();
            const int shift = 24 - 8 * pass;
            const uint32_t pre = sh_pre;
            for (int i = tid; i < n; i += 256) {
                uint32_t key = flipf(lg[i]);
                if (pass == 0 || (key >> (shift + 8)) == pre)
                    atomicAdd(&hist[(key >> shift) & 255u], 1u);
            }
            __syncthreads();
            if (tid == 0) {
                uint32_t rem = sh_rem;
                int d = 255;
                for (; d > 0; --d) {
                    uint32_t c = hist[d];
                    if (rem <= c) break;
                    rem -= c;
                }
                sh_rem = rem;
                sh_pre = (pre << 8) | (uint32_t)d;
            }
            __syncthreads();
        }
        const uint32_t T = sh_pre;
        for (int i = tid; i < n; i += 256) {
            uint32_t key = flipf(lg[i]);
            if (key >= T) {
                uint32_t pos = atomicAdd(&scnt2, 1u);
                if (pos < CAP) K[pos] = ((uint64_t)key << 32) | (uint32_t)(~(uint32_t)i);
            }
        }
        __syncthreads();
        cc = (int)min(scnt2, (uint32_t)CAP);
        if (c0 >= cc) return;
    }

    const int c = c0 + tid;
    const uint64_t myK = (c < cc) ? K[c] : ~0ull;
    int r = 0;
    int j = 0;
    for (; j + 8 <= cc; j += 8) {
        #pragma unroll
        for (int u = 0; u < 8; ++u) r += (int)(K[j + u] > myK);
    }
    for (; j < cc; ++j) r += (int)(K[j] > myK);

    if (c >= cc || r >= k) return;

    uint32_t key = (uint32_t)(myK >> 32);
    uint32_t ic  = ~(uint32_t)(myK & 0xFFFFFFFFu);
    const float* an = p.anchors[lvl] + (size_t)ic * 4;
    const float* dl = p.deltas[lvl] + ((size_t)img * n + ic) * 4;
    float a0 = an[0], a1 = an[1], a2 = an[2], a3 = an[3];
    float wa = a2 - a0, ha = a3 - a1;
    float cxa = a0 + 0.5f * wa, cya = a1 + 0.5f * ha;
    float dx = dl[0], dy = dl[1], dw = dl[2], dh = dl[3];
    const float SC = (float)4.135166556742356;  // log(1000/16)
    dw = fminf(dw, SC);
    dh = fminf(dh, SC);
    float cx = dx * wa + cxa, cy = dy * ha + cya;
    float w = wa * expf(dw), h = ha * expf(dh);
    float x1 = cx - 0.5f * w, y1 = cy - 0.5f * h;
    float x2 = cx + 0.5f * w, y2 = cy + 0.5f * h;
    x1 = fminf(fmaxf(x1, 0.0f), 1024.0f);
    y1 = fminf(fmaxf(y1, 0.0f), 1024.0f);
    x2 = fminf(fmaxf(x2, 0.0f), 1024.0f);
    y2 = fminf(fmaxf(y2, 0.0f), 1024.0f);
    float bw = x2 - x1, bh = y2 - y1;
    float score = (bw > 0.0f && bh > 0.0f) ? unflipf(key) : NEGV;
    const int slot = base + r;
    float* ob = cand_box + ((size_t)img * M_TOT + slot) * 4;
    ob[0] = x1; ob[1] = y1; ob[2] = x2; ob[3] = y2;
    cand_score[(size_t)img * M_TOT + slot] = score;
}

// ---------------------------------------------------------------------------
// NMS phase 1: suppression bit-matrix, COLUMN-BLOCK-MAJOR; j-boxes in lanes,
// v_readlane broadcasts — pure-VALU inner loop, no LDS.
// ---------------------------------------------------------------------------
__global__ void kIou(const float* __restrict__ cand_box,
                     uint64_t* __restrict__ tri, uint64_t* __restrict__ diag) {
    #pragma clang fp contract(off)
    const int blk = blockIdx.x;      // grp*64 + w*4 + c
    const int grp = blk >> 6;
    const int w   = (blk >> 2) & 15;
    const int ch  = blk & 3;
    const int img = grp / NLVL;
    const int lvl = grp % NLVL;
    const int k    = c_k[lvl];
    const int base = c_base[lvl];
    if (64 * w >= k) return;
    const int R  = min(64 * (w + 1), k);
    const int r0 = ch * 256;
    if (r0 >= R) return;
    const int jn = min(64, k - 64 * w);
    const float lo = (float)lvl * 2048.0f;
    const int tid = threadIdx.x;
    const int lane = tid & 63;

    const int jl = (lane < jn) ? lane : 0;
    const float4 jb = *(const float4*)(cand_box + ((size_t)img * M_TOT + base + 64 * w + jl) * 4);
    const float jx1r = jb.x + lo, jy1r = jb.y + lo;
    const float jx2r = jb.z + lo, jy2r = jb.w + lo;
    const float jarr = (jx2r - jx1r) * (jy2r - jy1r);

    const int r = r0 + tid;
    const bool act = r < R;
    float rx1 = 0, ry1 = 0, rx2 = 0, ry2 = 0, ra = 0;
    if (act) {
        const float4 b = *(const float4*)(cand_box + ((size_t)img * M_TOT + base + r) * 4);
        rx1 = b.x + lo; ry1 = b.y + lo; rx2 = b.z + lo; ry2 = b.w + lo;
        ra = (rx2 - rx1) * (ry2 - ry1);
    }

    uint64_t bits = 0ull;
    #pragma unroll 4
    for (int jj = 0; jj < jn; ++jj) {
        const float bx1 = rdlane_f(jx1r, jj);
        const float by1 = rdlane_f(jy1r, jj);
        const float bx2 = rdlane_f(jx2r, jj);
        const float by2 = rdlane_f(jy2r, jj);
        const float bar = rdlane_f(jarr, jj);
        const int j = 64 * w + jj;
        if (j > r) {
            float ltx = fmaxf(rx1, bx1);
            float lty = fmaxf(ry1, by1);
            float rbx = fminf(rx2, bx2);
            float rby = fminf(ry2, by2);
            float wx = fmaxf(rbx - ltx, 0.0f);
            float wy = fmaxf(rby - lty, 0.0f);
            float inter = wx * wy;
            float denom = ((ra + bar) - inter) + 1e-9f;
            if (inter / denom > 0.7f) bits |= (1ull << jj);
        }
    }

    if (act) {
        if ((r >> 6) == w) diag[(size_t)grp * 1024 + r] = bits;
        else               tri[(size_t)grp * TRI_W + 32 * w * (w - 1) + r] = bits;
    }
}

// ---------------------------------------------------------------------------
// NMS phase 2: greedy scan, ONE WAVE per group (separate kernel — fusing
// this into a 1024-thread block destroyed the load batching, round 15).
// Latency-batched gather, DPP OR-reduce, sparse scalar greedy.
// ---------------------------------------------------------------------------
__global__ void kScan(const float* __restrict__ cand_score,
                      const uint64_t* __restrict__ tri,
                      const uint64_t* __restrict__ diag,
                      uint32_t* __restrict__ kept) {
    const int grp = blockIdx.x;
    const int img = grp / NLVL;
    const int lvl = grp % NLVL;
    const int k    = c_k[lvl];
    const int base = c_base[lvl];
    const int lane = threadIdx.x;   // 64 threads = 1 wave

    __shared__ uint64_t sdiag[1024];
    __shared__ uint64_t sinv[16];

    const uint64_t* dg_g = diag + (size_t)grp * 1024;
    #pragma unroll
    for (int s = 0; s < 16; ++s) {
        const int r = 64 * s + lane;
        uint64_t d = (r < k) ? dg_g[r] : 0ull;
        sdiag[r] = d;
        float sc = (r < k) ? cand_score[(size_t)img * M_TOT + base + r] : NEGV;
        uint64_t iv = __ballot(sc <= -5e8f);
        if (lane == 0) sinv[s] = iv;
    }
    __syncthreads();

    const uint64_t* trig = tri + (size_t)grp * TRI_W;
    uint32_t mykept = 0u;
    const int nstage = (k + 63) >> 6;

    #pragma unroll 1
    for (int q = 0; q < nstage; ++q) {
        const uint64_t* tq = trig + 32 * q * (q - 1);
        uint64_t vals[15];
        #pragma unroll
        for (int s = 0; s < 15; ++s)
            if (s < q) vals[s] = tq[64 * s + lane];
        uint64_t v = 0ull;
        #pragma unroll
        for (int s = 0; s < 15; ++s)
            if (s < q) {
                uint64_t msk = (uint64_t)0 - (uint64_t)((mykept >> s) & 1u);
                v |= vals[s] & msk;
            }
        const uint32_t vlo = wave_or32((uint32_t)v);
        const uint32_t vhi = wave_or32((uint32_t)(v >> 32));
        const uint64_t invq = sinv[q];
        const uint32_t ivlo = __builtin_amdgcn_readfirstlane((uint32_t)invq);
        const uint32_t ivhi = __builtin_amdgcn_readfirstlane((uint32_t)(invq >> 32));
        uint64_t rem = ~((((uint64_t)ivhi << 32) | (uint64_t)ivlo)
                       | (((uint64_t)vhi  << 32) | (uint64_t)vlo));

        const uint64_t darrq = sdiag[64 * q + lane];
        const uint32_t dlo = (uint32_t)darrq, dhi = (uint32_t)(darrq >> 32);
        const uint64_t nz = __ballot(darrq != 0ull);

        uint64_t kw = 0ull;
        for (;;) {
            uint64_t t = rem & nz;
            if (t == 0ull) { kw |= rem; break; }
            const int m = (int)__builtin_ctzll(t);
            const uint64_t bm = 1ull << m;
            const uint64_t lowm = bm - 1ull;
            kw |= (rem & lowm) | bm;
            const uint64_t dg =
                ((uint64_t)(uint32_t)__builtin_amdgcn_readlane((int)dhi, m) << 32)
              |  (uint64_t)(uint32_t)__builtin_amdgcn_readlane((int)dlo, m);
            rem &= ~(lowm | bm | dg);
        }
        mykept |= ((uint32_t)((kw >> lane) & 1ull)) << q;
    }

    #pragma unroll
    for (int s = 0; s < 16; ++s) {
        const int r = 64 * s + lane;
        if (r < k)
            kept[(size_t)img * M_TOT + base + r] = (mykept >> s) & 1u;
    }
}

// ---------------------------------------------------------------------------
// Merge-rank + stable partition + output, one block (1024 thr) per image.
// Phase 3: wave-shuffle scan + one cross-wave LDS stage (1 barrier).
// ---------------------------------------------------------------------------
__device__ __forceinline__ int bs_count_ge(const uint32_t* a, int n, uint32_t x) {
    int lo = 0, hi = n;
    while (lo < hi) { int mid = (lo + hi) >> 1; if (a[mid] >= x) lo = mid + 1; else hi = mid; }
    return lo;
}
__device__ __forceinline__ int bs_count_gt(const uint32_t* a, int n, uint32_t x) {
    int lo = 0, hi = n;
    while (lo < hi) { int mid = (lo + hi) >> 1; if (a[mid] > x) lo = mid + 1; else hi = mid; }
    return lo;
}

__global__ void kMergeOut(const float* __restrict__ cand_box,
                          const float* __restrict__ cand_score,
                          const uint32_t* __restrict__ kept,
                          float* __restrict__ out) {
    const int img = blockIdx.x;
    const int tid = threadIdx.x;   // 1024
    const int lane = tid & 63, wave = tid >> 6;

    __shared__ uint32_t vkey[NLVL * 1024];  // compacted valid keys, desc
    __shared__ uint32_t ord[M_TOT];         // merged order: slot | kept<<31
    __shared__ uint32_t wsum[NLVL][16];
    __shared__ int wtot[16];

    // ---- Phase 1: per-level valid ballot-scan ----
    uint32_t mykey[NLVL];
    int myvalid[NLVL], mylower[NLVL];
    #pragma unroll
    for (int L = 0; L < NLVL; ++L) {
        const int kL = c_k[L];
        const bool act = tid < kL;
        float s = act ? cand_score[(size_t)img * M_TOT + c_base[L] + tid] : NEGV;
        bool valid = act && (s > -5e8f);
        uint64_t mask = __ballot(valid);
        mylower[L] = (int)__popcll(mask & ((1ull << lane) - 1ull));
        if (lane == 0) wsum[L][wave] = (uint32_t)__popcll(mask);
        mykey[L] = flipf(s);
        myvalid[L] = valid ? 1 : 0;
    }
    __syncthreads();

    int nv[NLVL], myvpre[NLVL];
    #pragma unroll
    for (int L = 0; L < NLVL; ++L) {
        int pw = 0, tot = 0;
        #pragma unroll
        for (int w = 0; w < 16; ++w) {
            if (w < wave) pw += (int)wsum[L][w];
            tot += (int)wsum[L][w];
        }
        nv[L] = tot;
        myvpre[L] = pw + mylower[L];
        if (tid < c_k[L] && myvalid[L])
            vkey[L * 1024 + myvpre[L]] = mykey[L];
    }
    int totalValid = 0;
    #pragma unroll
    for (int L = 0; L < NLVL; ++L) totalValid += nv[L];
    __syncthreads();

    // ---- Phase 2: merge-rank each element, scatter into ord ----
    int invBase = totalValid;
    #pragma unroll
    for (int L = 0; L < NLVL; ++L) {
        const int kL = c_k[L];
        if (tid < kL) {
            const int slot = c_base[L] + tid;
            if (myvalid[L]) {
                const uint32_t x = mykey[L];
                int pos = myvpre[L];
                #pragma unroll
                for (int Lp = 0; Lp < NLVL; ++Lp) {
                    if (Lp == L) continue;
                    pos += (Lp < L) ? bs_count_ge(&vkey[Lp * 1024], nv[Lp], x)
                                    : bs_count_gt(&vkey[Lp * 1024], nv[Lp], x);
                }
                const uint32_t kp = kept[(size_t)img * M_TOT + slot];
                ord[pos] = (uint32_t)slot | (kp << 31);
            } else {
                const int inv_idx = tid - myvpre[L];
                ord[invBase + inv_idx] = (uint32_t)slot;  // kept=0
            }
        }
        invBase += (kL - nv[L]);
    }
    __syncthreads();

    // ---- Phase 3: stable partition by kept flag, write output ----
    const int PT = 5;
    const int pos0 = tid * PT;
    int flags[PT];
    uint32_t slots[PT];
    int lsum = 0;
    #pragma unroll
    for (int q = 0; q < PT; ++q) {
        int pp = pos0 + q;
        int kf = 0; uint32_t sl = 0;
        if (pp < M_TOT) {
            uint32_t o = ord[pp];
            sl = o & 0x7FFFFFFFu;
            kf = (int)(o >> 31);
        }
        flags[q] = kf; slots[q] = sl; lsum += kf;
    }
    int incl = lsum;
    #pragma unroll
    for (int off = 1; off < 64; off <<= 1) {
        int t = __shfl_up(incl, off, 64);
        if (lane >= off) incl += t;
    }
    if (lane == 63) wtot[wave] = incl;
    __syncthreads();
    int wpre = 0, total = 0;
    #pragma unroll
    for (int w = 0; w < 16; ++w) {
        int v = wtot[w];
        if (w < wave) wpre += v;
        total += v;
    }
    const int excl = wpre + (incl - lsum);

    int run = 0;
    #pragma unroll
    for (int q = 0; q < PT; ++q) {
        int pp = pos0 + q;
        if (pp >= M_TOT) break;
        int kf = flags[q];
        int kbefore = excl + run;
        run += kf;
        int oidx = kf ? kbefore : (total + (pp - kbefore));
        if (oidx < POST_K) {
            uint32_t sl = slots[q];
            const float4 b = *(const float4*)(cand_box + ((size_t)img * M_TOT + sl) * 4);
            float* ob = out + ((size_t)img * POST_K + oidx) * 4;
            ob[0] = b.x; ob[1] = b.y; ob[2] = b.z; ob[3] = b.w;
            out[NIMG * POST_K * 4 + (size_t)img * POST_K + oidx] =
                kf ? cand_score[(size_t)img * M_TOT + sl] : NEGV;
        }
    }
}

extern "C" void kernel_launch(void* const* d_in, const int* in_sizes, int n_in,
                              void* d_out, int out_size, void* d_ws, size_t ws_size,
                              hipStream_t stream) {
    Ptrs p;
    for (int l = 0; l < NLVL; ++l) {
        p.logits[l]  = (const float*)d_in[3 * l + 0];
        p.deltas[l]  = (const float*)d_in[3 * l + 1];
        p.anchors[l] = (const float*)d_in[3 * l + 2];
    }

    // workspace layout (~12 MB)
    char* w = (char*)d_ws;
    float* cand_box   = (float*)w;        w += (size_t)NIMG * M_TOT * 4 * sizeof(float);
    float* cand_score = (float*)w;        w += (size_t)NIMG * M_TOT * sizeof(float);
    uint32_t* kept        = (uint32_t*)w; w += (size_t)NIMG * M_TOT * sizeof(uint32_t);
    uint64_t* pk2         = (uint64_t*)w; w += (size_t)NIMG * BPI * UCAP * sizeof(uint64_t);
    uint64_t* tri         = (uint64_t*)w; w += (size_t)NGRP * TRI_W * sizeof(uint64_t);
    uint64_t* diag        = (uint64_t*)w; w += (size_t)NGRP * 1024 * sizeof(uint64_t);
    uint32_t* ucnt        = (uint32_t*)w; w += (size_t)NIMG * BPI * sizeof(uint32_t);

    kCompactSpec<<<NIMG * BPI,       256, 0, stream>>>(p, ucnt, pk2);
    kRankDecode <<<NGRP * RD_SPLIT,  256, 0, stream>>>(p, ucnt, pk2, cand_box, cand_score);
    kIou        <<<NGRP * 64,        256, 0, stream>>>(cand_box, tri, diag);
    kScan       <<<NGRP,              64, 0, stream>>>(cand_score, tri, diag, kept);
    kMergeOut   <<<NIMG,            1024, 0, stream>>>(cand_box, cand_score, kept, (float*)d_out);
}